// Round 1
// baseline (1760.409 us; speedup 1.0000x reference)
//
#include <hip/hip_runtime.h>

#define N_SP 4096   // H*W
#define C_IN 512
#define CQ   64

// ---------------------------------------------------------------------------
// Kernel 1: fused QKV projection.
// Q[b][o][n] = sum_c Wq[o][c] x[b][c][n]   (o in [0,64))
// K[b][o][n] = sum_c Wk[o][c] x[b][c][n]
// V[b][o][n] = sum_c Wv[o][c] x[b][c][n]   (o in [0,512))
// Treated as one GEMM with 640 output rows per batch, tiled 64(M) x 128(N),
// 256 threads, 4x8 micro-tile, K-chunks of 16 staged in LDS.
// ---------------------------------------------------------------------------
__global__ __launch_bounds__(256, 4)
void proj_qkv(const float* __restrict__ x,
              const float* __restrict__ Wq,
              const float* __restrict__ Wk,
              const float* __restrict__ Wv,
              float* __restrict__ Qb,
              float* __restrict__ Kb,
              float* __restrict__ Vb)
{
    const int tid = threadIdx.x;
    const int nt  = blockIdx.x;   // 32 n-tiles of 128
    const int mt  = blockIdx.y;   // 10 m-tiles of 64 (0:Q, 1:K, 2..9:V)
    const int b   = blockIdx.z;   // 4 batches
    const int row0 = mt * 64;

    const float* __restrict__ Wsrc;
    float* __restrict__ O;
    int wrow0;
    if (row0 < 64)       { Wsrc = Wq; wrow0 = row0;       O = Qb + ((size_t)b*CQ   + wrow0)*N_SP; }
    else if (row0 < 128) { Wsrc = Wk; wrow0 = row0 - 64;  O = Kb + ((size_t)b*CQ   + wrow0)*N_SP; }
    else                 { Wsrc = Wv; wrow0 = row0 - 128; O = Vb + ((size_t)b*C_IN + wrow0)*N_SP; }

    __shared__ float Wl[64][20];    // 64 rows x 16 k (pad to 20 -> 16B-aligned rows)
    __shared__ float Xl[16][132];   // 16 k x 128 n (pad 132 keeps float4 alignment)

    float acc[4][8];
    #pragma unroll
    for (int i = 0; i < 4; ++i)
        #pragma unroll
        for (int j = 0; j < 8; ++j) acc[i][j] = 0.f;

    const float* xb = x + ((size_t)b*C_IN)*N_SP + nt*128;
    const int tm = tid >> 4, tn = tid & 15;

    for (int k0 = 0; k0 < C_IN; k0 += 16) {
        {   // stage W tile: 64x16, 4 floats per thread
            const int r = tid >> 2, c = (tid & 3) * 4;
            *reinterpret_cast<float4*>(&Wl[r][c]) =
                *reinterpret_cast<const float4*>(&Wsrc[(size_t)(wrow0 + r)*C_IN + k0 + c]);
        }
        {   // stage X tile: 16x128, 8 floats per thread (coalesced)
            const int r = tid >> 5, c = (tid & 31) * 4;
            *reinterpret_cast<float4*>(&Xl[r][c]) =
                *reinterpret_cast<const float4*>(&xb[(size_t)(k0 + r)*N_SP + c]);
            *reinterpret_cast<float4*>(&Xl[r + 8][c]) =
                *reinterpret_cast<const float4*>(&xb[(size_t)(k0 + r + 8)*N_SP + c]);
        }
        __syncthreads();
        #pragma unroll
        for (int kk = 0; kk < 16; ++kk) {
            float a[4];
            #pragma unroll
            for (int i = 0; i < 4; ++i) a[i] = Wl[tm*4 + i][kk];   // broadcast reads
            float xr[8];
            // two float4 groups at n = tn*4 and n = 64 + tn*4 -> 2-way banks (free)
            *reinterpret_cast<float4*>(&xr[0]) = *reinterpret_cast<const float4*>(&Xl[kk][tn*4]);
            *reinterpret_cast<float4*>(&xr[4]) = *reinterpret_cast<const float4*>(&Xl[kk][64 + tn*4]);
            #pragma unroll
            for (int i = 0; i < 4; ++i)
                #pragma unroll
                for (int j = 0; j < 8; ++j)
                    acc[i][j] = fmaf(a[i], xr[j], acc[i][j]);
        }
        __syncthreads();
    }

    #pragma unroll
    for (int i = 0; i < 4; ++i) {
        float* dst = O + (size_t)(tm*4 + i)*N_SP + nt*128;
        float4 o0 = make_float4(acc[i][0], acc[i][1], acc[i][2], acc[i][3]);
        float4 o1 = make_float4(acc[i][4], acc[i][5], acc[i][6], acc[i][7]);
        *reinterpret_cast<float4*>(&dst[tn*4])      = o0;
        *reinterpret_cast<float4*>(&dst[64 + tn*4]) = o1;
    }
}

// ---------------------------------------------------------------------------
// Kernel 2: fused flash attention + gamma*out + x.
// One block per (batch, 64-query tile); 512 threads.
// Per 64-key chunk:
//   phase A: S[i][j] = sum_o Ql[o][i]*Kl[o][j] (16x32 thread grid, 4i x 2j),
//            online softmax stats (shfl over the 32 j-lanes), P -> LDS (as Pt[j][i]).
//   phase B: acc[c][i] = acc*r + sum_j V[c][j] * Pt[j][i];
//            each thread owns c = tc+128*cc (4 chans) x i = ti2*16.. (16 queries).
// Epilogue: out = gamma*acc/l + x, written coalesced via LDS transpose.
// ---------------------------------------------------------------------------
__global__ __launch_bounds__(512, 2)
void attn_fused(const float* __restrict__ x,
                const float* __restrict__ Qb,
                const float* __restrict__ Kb,
                const float* __restrict__ Vb,
                const float* __restrict__ gamma_p,
                float* __restrict__ out)
{
    const int tid = threadIdx.x;
    const int it  = blockIdx.x;   // 64 query tiles
    const int b   = blockIdx.y;   // 4 batches
    const int i0g = it * 64;

    __shared__ float Ql[64][68];   // [o][i]
    __shared__ float Kl[64][68];   // [o][j]
    __shared__ float Pt[64][68];   // [j][i]
    __shared__ float m_sh[64], l_sh[64], r_sh[64];

    {   // stage Q tile [64 o][64 i], coalesced
        const int o = tid >> 3, c = (tid & 7) * 8;
        const float* src = Qb + ((size_t)b*CQ + o)*N_SP + i0g + c;
        *reinterpret_cast<float4*>(&Ql[o][c])     = *reinterpret_cast<const float4*>(&src[0]);
        *reinterpret_cast<float4*>(&Ql[o][c + 4]) = *reinterpret_cast<const float4*>(&src[4]);
    }
    if (tid < 64) { m_sh[tid] = -1e30f; l_sh[tid] = 0.f; }

    const int ti  = tid >> 5, tj = tid & 31;   // phase A ids
    const int ti2 = tid >> 7, tc = tid & 127;  // phase B ids
    const int ib  = ti2 * 16;

    const float* Kg = Kb + (size_t)b*CQ*N_SP;
    const float* Vg = Vb + (size_t)b*C_IN*N_SP;

    float accv[4][16];
    #pragma unroll
    for (int cc = 0; cc < 4; ++cc)
        #pragma unroll
        for (int il = 0; il < 16; ++il) accv[cc][il] = 0.f;

    __syncthreads();

    for (int jb = 0; jb < N_SP; jb += 64) {
        {   // stage K chunk [64 o][64 j]
            const int o = tid >> 3, c = (tid & 7) * 8;
            const float* src = Kg + (size_t)o*N_SP + jb + c;
            *reinterpret_cast<float4*>(&Kl[o][c])     = *reinterpret_cast<const float4*>(&src[0]);
            *reinterpret_cast<float4*>(&Kl[o][c + 4]) = *reinterpret_cast<const float4*>(&src[4]);
        }
        __syncthreads();

        // ---- phase A ----
        float s[4][2];
        #pragma unroll
        for (int ii = 0; ii < 4; ++ii) { s[ii][0] = 0.f; s[ii][1] = 0.f; }
        #pragma unroll 16
        for (int o = 0; o < 64; ++o) {
            float q[4];
            *reinterpret_cast<float4*>(&q[0]) =
                *reinterpret_cast<const float4*>(&Ql[o][ti*4]);      // broadcast per 32 lanes
            float2 k2 = *reinterpret_cast<const float2*>(&Kl[o][tj*2]);
            #pragma unroll
            for (int ii = 0; ii < 4; ++ii) {
                s[ii][0] = fmaf(q[ii], k2.x, s[ii][0]);
                s[ii][1] = fmaf(q[ii], k2.y, s[ii][1]);
            }
        }

        float p[4][2], rr[4], nm[4], ls[4];
        #pragma unroll
        for (int ii = 0; ii < 4; ++ii) {
            float mc = fmaxf(s[ii][0], s[ii][1]);
            mc = fmaxf(mc, __shfl_xor(mc, 1));
            mc = fmaxf(mc, __shfl_xor(mc, 2));
            mc = fmaxf(mc, __shfl_xor(mc, 4));
            mc = fmaxf(mc, __shfl_xor(mc, 8));
            mc = fmaxf(mc, __shfl_xor(mc, 16));   // row-chunk max over 64 j
            const float mo = m_sh[ti*4 + ii];     // read precedes lockstep write below
            const float mn = fmaxf(mo, mc);
            rr[ii]   = __expf(mo - mn);
            p[ii][0] = __expf(s[ii][0] - mn);
            p[ii][1] = __expf(s[ii][1] - mn);
            float sum = p[ii][0] + p[ii][1];
            sum += __shfl_xor(sum, 1);
            sum += __shfl_xor(sum, 2);
            sum += __shfl_xor(sum, 4);
            sum += __shfl_xor(sum, 8);
            sum += __shfl_xor(sum, 16);
            nm[ii] = mn; ls[ii] = sum;
        }
        {
            const int j0 = tj * 2;
            *reinterpret_cast<float4*>(&Pt[j0][ti*4]) =
                make_float4(p[0][0], p[1][0], p[2][0], p[3][0]);
            *reinterpret_cast<float4*>(&Pt[j0 + 1][ti*4]) =
                make_float4(p[0][1], p[1][1], p[2][1], p[3][1]);
        }
        if (tj == 0) {
            #pragma unroll
            for (int ii = 0; ii < 4; ++ii) {
                const int i = ti*4 + ii;
                m_sh[i] = nm[ii];
                l_sh[i] = l_sh[i] * rr[ii] + ls[ii];
                r_sh[i] = rr[ii];
            }
        }
        __syncthreads();

        // ---- phase B ----
        #pragma unroll
        for (int il = 0; il < 16; ++il) {
            const float rf = r_sh[ib + il];
            #pragma unroll
            for (int cc = 0; cc < 4; ++cc) accv[cc][il] *= rf;
        }
        #pragma unroll
        for (int js = 0; js < 8; ++js) {
            float va[4][8];
            #pragma unroll
            for (int cc = 0; cc < 4; ++cc) {
                const float* vp = Vg + (size_t)(tc + 128*cc)*N_SP + jb + js*8;
                *reinterpret_cast<float4*>(&va[cc][0]) = *reinterpret_cast<const float4*>(vp);
                *reinterpret_cast<float4*>(&va[cc][4]) = *reinterpret_cast<const float4*>(vp + 4);
            }
            #pragma unroll
            for (int jj = 0; jj < 8; ++jj) {
                const int j = js*8 + jj;
                float pv[16];   // uniform address across wave -> LDS broadcast
                *reinterpret_cast<float4*>(&pv[0])  = *reinterpret_cast<const float4*>(&Pt[j][ib + 0]);
                *reinterpret_cast<float4*>(&pv[4])  = *reinterpret_cast<const float4*>(&Pt[j][ib + 4]);
                *reinterpret_cast<float4*>(&pv[8])  = *reinterpret_cast<const float4*>(&Pt[j][ib + 8]);
                *reinterpret_cast<float4*>(&pv[12]) = *reinterpret_cast<const float4*>(&Pt[j][ib + 12]);
                #pragma unroll
                for (int cc = 0; cc < 4; ++cc) {
                    const float v = va[cc][jj];
                    #pragma unroll
                    for (int il = 0; il < 16; ++il)
                        accv[cc][il] = fmaf(v, pv[il], accv[cc][il]);
                }
            }
        }
        __syncthreads();
    }

    // ---- epilogue: out = gamma * acc / l + x, coalesced via LDS transpose ----
    const float g = gamma_p[0];
    float rl[16];
    #pragma unroll
    for (int il = 0; il < 16; ++il) rl[il] = 1.0f / l_sh[ib + il];

    #pragma unroll
    for (int pass = 0; pass < 8; ++pass) {
        __syncthreads();
        const int cc = pass >> 1;
        const int tcbase = (pass & 1) * 64;
        if (tc >= tcbase && tc < tcbase + 64) {
            const int cl = tc - tcbase;
            #pragma unroll
            for (int il = 0; il < 16; ++il)
                Ql[cl][ib + il] = accv[cc][il] * rl[il];
        }
        __syncthreads();
        {
            const int cl = tid >> 3, col = (tid & 7) * 8;
            const size_t base = ((size_t)b*C_IN + pass*64 + cl)*N_SP + i0g + col;
            float4 v0 = *reinterpret_cast<const float4*>(&Ql[cl][col]);
            float4 v1 = *reinterpret_cast<const float4*>(&Ql[cl][col + 4]);
            float4 x0 = *reinterpret_cast<const float4*>(&x[base]);
            float4 x1 = *reinterpret_cast<const float4*>(&x[base + 4]);
            float4 o0 = make_float4(fmaf(g, v0.x, x0.x), fmaf(g, v0.y, x0.y),
                                    fmaf(g, v0.z, x0.z), fmaf(g, v0.w, x0.w));
            float4 o1 = make_float4(fmaf(g, v1.x, x1.x), fmaf(g, v1.y, x1.y),
                                    fmaf(g, v1.z, x1.z), fmaf(g, v1.w, x1.w));
            *reinterpret_cast<float4*>(&out[base])     = o0;
            *reinterpret_cast<float4*>(&out[base + 4]) = o1;
        }
    }
}

extern "C" void kernel_launch(void* const* d_in, const int* in_sizes, int n_in,
                              void* d_out, int out_size, void* d_ws, size_t ws_size,
                              hipStream_t stream)
{
    (void)in_sizes; (void)n_in; (void)out_size; (void)ws_size;
    const float* x  = (const float*)d_in[0];
    const float* Wq = (const float*)d_in[1];
    const float* Wk = (const float*)d_in[2];
    const float* Wv = (const float*)d_in[3];
    const float* gm = (const float*)d_in[4];
    float* out = (float*)d_out;

    // workspace: Q (4 MB) | K (4 MB) | V (32 MB) = 40 MB
    float* Qb = (float*)d_ws;
    float* Kb = Qb + (size_t)4*CQ*N_SP;
    float* Vb = Kb + (size_t)4*CQ*N_SP;

    dim3 g1(32, 10, 4);
    proj_qkv<<<g1, 256, 0, stream>>>(x, Wq, Wk, Wv, Qb, Kb, Vb);
    dim3 g2(64, 4);
    attn_fused<<<g2, 512, 0, stream>>>(x, Qb, Kb, Vb, gm, out);
}

// Round 2
// 681.504 us; speedup vs baseline: 2.5831x; 2.5831x over previous
//
#include <hip/hip_runtime.h>

#define N_SP 4096   // H*W
#define C_IN 512
#define CQ   64

typedef __attribute__((ext_vector_type(8))) short bf16x8;
typedef __attribute__((ext_vector_type(4))) float f32x4;
typedef unsigned short ushort_t;

__device__ __forceinline__ unsigned int f2bf(float f) {
    unsigned int u = __float_as_uint(f);
    u += 0x7FFFu + ((u >> 16) & 1u);   // RNE
    return u >> 16;
}

// ---------------------------------------------------------------------------
// Kernel 1: fused QKV projection (fp32 GEMM as in R1).
// Q,K written fp32 [b][o][n]; V written bf16 [b][c][n] (only attn consumes V).
// ---------------------------------------------------------------------------
__global__ __launch_bounds__(256, 4)
void proj_qkv(const float* __restrict__ x,
              const float* __restrict__ Wq,
              const float* __restrict__ Wk,
              const float* __restrict__ Wv,
              float* __restrict__ Qb,
              float* __restrict__ Kb,
              ushort_t* __restrict__ Vbf)
{
    const int tid = threadIdx.x;
    const int nt  = blockIdx.x;   // 32 n-tiles of 128
    const int mt  = blockIdx.y;   // 10 m-tiles of 64 (0:Q, 1:K, 2..9:V)
    const int b   = blockIdx.z;
    const int row0 = mt * 64;

    const float* __restrict__ Wsrc;
    int wrow0, kind;
    if (row0 < 64)       { Wsrc = Wq; wrow0 = row0;       kind = 0; }
    else if (row0 < 128) { Wsrc = Wk; wrow0 = row0 - 64;  kind = 1; }
    else                 { Wsrc = Wv; wrow0 = row0 - 128; kind = 2; }

    __shared__ float Wl[64][20];
    __shared__ float Xl[16][132];

    float acc[4][8];
    #pragma unroll
    for (int i = 0; i < 4; ++i)
        #pragma unroll
        for (int j = 0; j < 8; ++j) acc[i][j] = 0.f;

    const float* xb = x + ((size_t)b*C_IN)*N_SP + nt*128;
    const int tm = tid >> 4, tn = tid & 15;

    for (int k0 = 0; k0 < C_IN; k0 += 16) {
        {
            const int r = tid >> 2, c = (tid & 3) * 4;
            *reinterpret_cast<float4*>(&Wl[r][c]) =
                *reinterpret_cast<const float4*>(&Wsrc[(size_t)(wrow0 + r)*C_IN + k0 + c]);
        }
        {
            const int r = tid >> 5, c = (tid & 31) * 4;
            *reinterpret_cast<float4*>(&Xl[r][c]) =
                *reinterpret_cast<const float4*>(&xb[(size_t)(k0 + r)*N_SP + c]);
            *reinterpret_cast<float4*>(&Xl[r + 8][c]) =
                *reinterpret_cast<const float4*>(&xb[(size_t)(k0 + r + 8)*N_SP + c]);
        }
        __syncthreads();
        #pragma unroll
        for (int kk = 0; kk < 16; ++kk) {
            float a[4];
            #pragma unroll
            for (int i = 0; i < 4; ++i) a[i] = Wl[tm*4 + i][kk];
            float xr[8];
            *reinterpret_cast<float4*>(&xr[0]) = *reinterpret_cast<const float4*>(&Xl[kk][tn*4]);
            *reinterpret_cast<float4*>(&xr[4]) = *reinterpret_cast<const float4*>(&Xl[kk][64 + tn*4]);
            #pragma unroll
            for (int i = 0; i < 4; ++i)
                #pragma unroll
                for (int j = 0; j < 8; ++j)
                    acc[i][j] = fmaf(a[i], xr[j], acc[i][j]);
        }
        __syncthreads();
    }

    if (kind < 2) {
        float* O = (kind == 0 ? Qb : Kb) + ((size_t)b*CQ + wrow0)*N_SP + nt*128;
        #pragma unroll
        for (int i = 0; i < 4; ++i) {
            float* dst = O + (size_t)(tm*4 + i)*N_SP;
            *reinterpret_cast<float4*>(&dst[tn*4]) =
                make_float4(acc[i][0], acc[i][1], acc[i][2], acc[i][3]);
            *reinterpret_cast<float4*>(&dst[64 + tn*4]) =
                make_float4(acc[i][4], acc[i][5], acc[i][6], acc[i][7]);
        }
    } else {
        ushort_t* O = Vbf + ((size_t)b*C_IN + wrow0)*N_SP + nt*128;
        #pragma unroll
        for (int i = 0; i < 4; ++i) {
            ushort_t* dst = O + (size_t)(tm*4 + i)*N_SP;
            ushort4 h0, h1;
            h0.x = (ushort_t)f2bf(acc[i][0]); h0.y = (ushort_t)f2bf(acc[i][1]);
            h0.z = (ushort_t)f2bf(acc[i][2]); h0.w = (ushort_t)f2bf(acc[i][3]);
            h1.x = (ushort_t)f2bf(acc[i][4]); h1.y = (ushort_t)f2bf(acc[i][5]);
            h1.z = (ushort_t)f2bf(acc[i][6]); h1.w = (ushort_t)f2bf(acc[i][7]);
            *reinterpret_cast<ushort4*>(&dst[tn*4])      = h0;
            *reinterpret_cast<ushort4*>(&dst[64 + tn*4]) = h1;
        }
    }
}

// ---------------------------------------------------------------------------
// Kernel 2: transpose+convert Q,K: fp32 [b][64][4096] -> bf16 [b][4096][64].
// ---------------------------------------------------------------------------
__global__ __launch_bounds__(256, 4)
void transpose_qk(const float* __restrict__ Qb, const float* __restrict__ Kb,
                  ushort_t* __restrict__ Qt, ushort_t* __restrict__ Kt)
{
    const int tid = threadIdx.x;
    const int nt  = blockIdx.x;          // 64 tiles of 64 n
    const int sel = blockIdx.y;          // 0: Q, 1: K
    const int b   = blockIdx.z;
    const float* src = sel ? Kb : Qb;
    ushort_t*    dst = sel ? Kt : Qt;

    __shared__ float Tl[64][65];
    {
        const int o  = tid >> 2;
        const int nc = (tid & 3) * 16;
        const float* s = src + ((size_t)b*CQ + o)*N_SP + nt*64 + nc;
        #pragma unroll
        for (int q = 0; q < 4; ++q) {
            float4 v = *reinterpret_cast<const float4*>(s + q*4);
            Tl[o][nc + q*4 + 0] = v.x; Tl[o][nc + q*4 + 1] = v.y;
            Tl[o][nc + q*4 + 2] = v.z; Tl[o][nc + q*4 + 3] = v.w;
        }
    }
    __syncthreads();
    {
        const int n  = tid >> 2;
        const int k0 = (tid & 3) * 16;
        unsigned int wds[8];
        #pragma unroll
        for (int k = 0; k < 16; k += 2) {
            wds[k >> 1] = f2bf(Tl[k0 + k][n]) | (f2bf(Tl[k0 + k + 1][n]) << 16);
        }
        ushort_t* d = dst + (((size_t)b*N_SP + nt*64 + n) * 64 + k0);
        reinterpret_cast<uint4*>(d)[0] = make_uint4(wds[0], wds[1], wds[2], wds[3]);
        reinterpret_cast<uint4*>(d)[1] = make_uint4(wds[4], wds[5], wds[6], wds[7]);
    }
}

// ---------------------------------------------------------------------------
// Kernel 3: MFMA flash attention + gamma*out + x.
// Block: 256 threads / 4 waves. QT=64 queries, KB=64 keys/chunk, 128 channels.
// Wave w owns queries [16w,16w+16): computes S^T = K·Q^T (softmax lane-local,
// query = lane&15), bounces P through per-wave swizzled LDS into A-frag
// layout, accumulates O = P·V^T over its 8 channel tiles.
// A/B frags both use slot->k map k = (lane>>4)*8+e, so matmuls are exact
// under any HW k-permutation; C/D layout col=lane&15,row=(lane>>4)*4+reg
// is the HW-verified one.
// ---------------------------------------------------------------------------
__global__ __launch_bounds__(256, 4)
void attn_mfma(const float* __restrict__ x,
               const ushort_t* __restrict__ Qt,
               const ushort_t* __restrict__ Kt,
               const ushort_t* __restrict__ Vbf,
               const float* __restrict__ gamma_p,
               float* __restrict__ out)
{
    const int tid  = threadIdx.x;
    const int lane = tid & 63;
    const int w    = tid >> 6;      // wave 0..3
    const int g    = lane >> 4;     // k-group 0..3
    const int c16  = lane & 15;

    const int it  = blockIdx.x;     // 64 query tiles
    const int c0  = blockIdx.y * 128;
    const int b   = blockIdx.z;
    const int i0g = it * 64;

    __shared__ ushort_t Ql[64*64];
    __shared__ ushort_t Kl[64*64];
    __shared__ ushort_t Pl[4][16*64];

    // ---- stage Q tile (bf16 [i][o], XOR-swizzled rows of 128B) ----
    {
        const int r  = tid >> 3;
        const int bc = (tid & 7) * 16;
        const char* src = (const char*)(Qt + ((size_t)b*N_SP + i0g)*64);
        #pragma unroll
        for (int p = 0; p < 2; ++p) {
            const int row = r + p*32;
            uint4 v = *reinterpret_cast<const uint4*>(src + row*128 + bc);
            *reinterpret_cast<uint4*>((char*)Ql + row*128 + (bc ^ ((row & 7) << 4))) = v;
        }
    }
    __syncthreads();

    const int aswz = (c16 & 7) << 4;
    const int arow = c16 * 128;
    // B-frag of Q^T for this wave's 16 queries (rows 16w+c16), both k-steps
    const bf16x8 qf0 = *reinterpret_cast<const bf16x8*>(
        (const char*)Ql + (16*w + c16)*128 + ((g*16) ^ aswz));
    const bf16x8 qf1 = *reinterpret_cast<const bf16x8*>(
        (const char*)Ql + (16*w + c16)*128 + ((64 + g*16) ^ aswz));

    float m_run = -1e30f, l_run = 0.f;
    f32x4 acc[8];
    #pragma unroll
    for (int ct = 0; ct < 8; ++ct) acc[ct] = (f32x4){0.f, 0.f, 0.f, 0.f};

    for (int jb = 0; jb < N_SP; jb += 64) {
        __syncthreads();   // previous chunk's readers done before Kl overwrite
        {
            const int r  = tid >> 3;
            const int bc = (tid & 7) * 16;
            const char* src = (const char*)(Kt + ((size_t)b*N_SP + jb)*64);
            #pragma unroll
            for (int p = 0; p < 2; ++p) {
                const int row = r + p*32;
                uint4 v = *reinterpret_cast<const uint4*>(src + row*128 + bc);
                *reinterpret_cast<uint4*>((char*)Kl + row*128 + (bc ^ ((row & 7) << 4))) = v;
            }
        }
        __syncthreads();

        // ---- S^T = K·Q^T : wave w computes S^T[0..64)[16w..16w+16) ----
        f32x4 sf[4];
        #pragma unroll
        for (int jt = 0; jt < 4; ++jt) {
            const int krow = (jt*16 + c16) * 128;
            const bf16x8 kf0 = *reinterpret_cast<const bf16x8*>(
                (const char*)Kl + krow + ((g*16) ^ aswz));
            const bf16x8 kf1 = *reinterpret_cast<const bf16x8*>(
                (const char*)Kl + krow + ((64 + g*16) ^ aswz));
            f32x4 z = (f32x4){0.f, 0.f, 0.f, 0.f};
            z = __builtin_amdgcn_mfma_f32_16x16x32_bf16(kf0, qf0, z, 0, 0, 0);
            z = __builtin_amdgcn_mfma_f32_16x16x32_bf16(kf1, qf1, z, 0, 0, 0);
            sf[jt] = z;
        }

        // ---- online softmax; lane owns query i = 16w + c16 (16 j-vals) ----
        float cmax = sf[0][0];
        #pragma unroll
        for (int jt = 0; jt < 4; ++jt)
            #pragma unroll
            for (int q = 0; q < 4; ++q) cmax = fmaxf(cmax, sf[jt][q]);
        cmax = fmaxf(cmax, __shfl_xor(cmax, 16));
        cmax = fmaxf(cmax, __shfl_xor(cmax, 32));
        const float mn = fmaxf(m_run, cmax);
        const float rr = __expf(m_run - mn);
        float csum = 0.f;
        #pragma unroll
        for (int jt = 0; jt < 4; ++jt)
            #pragma unroll
            for (int q = 0; q < 4; ++q) {
                const float p = __expf(sf[jt][q] - mn);
                csum += p;
                sf[jt][q] = p;
            }
        csum += __shfl_xor(csum, 16);
        csum += __shfl_xor(csum, 32);
        l_run = l_run * rr + csum;
        m_run = mn;

        // ---- P (C/D layout) -> bf16 -> per-wave LDS -> A-frag layout ----
        #pragma unroll
        for (int jt = 0; jt < 4; ++jt) {
            uint2 pk;
            pk.x = f2bf(sf[jt][0]) | (f2bf(sf[jt][1]) << 16);
            pk.y = f2bf(sf[jt][2]) | (f2bf(sf[jt][3]) << 16);
            *reinterpret_cast<uint2*>((char*)Pl[w] + arow + ((jt*32 + g*8) ^ aswz)) = pk;
        }
        __asm__ volatile("s_waitcnt lgkmcnt(0)" ::: "memory");   // same-wave RAW
        const bf16x8 pa0 = *reinterpret_cast<const bf16x8*>(
            (const char*)Pl[w] + arow + ((g*16) ^ aswz));
        const bf16x8 pa1 = *reinterpret_cast<const bf16x8*>(
            (const char*)Pl[w] + arow + ((64 + g*16) ^ aswz));

        // ---- rescale O (C/D rows are queries g*4+q of rowtile w) ----
        float rb[4];
        #pragma unroll
        for (int q = 0; q < 4; ++q) rb[q] = __shfl(rr, g*4 + q);
        #pragma unroll
        for (int ct = 0; ct < 8; ++ct)
            #pragma unroll
            for (int q = 0; q < 4; ++q) acc[ct][q] *= rb[q];

        // ---- O += P·V^T ----
        const ushort_t* Vrow = Vbf + ((size_t)b*C_IN + c0 + c16)*N_SP + jb + g*8;
        #pragma unroll
        for (int ks = 0; ks < 2; ++ks) {
            const bf16x8 pa = ks ? pa1 : pa0;
            #pragma unroll
            for (int ct = 0; ct < 8; ++ct) {
                const bf16x8 vf = *reinterpret_cast<const bf16x8*>(
                    Vrow + (size_t)(ct*16)*N_SP + ks*32);
                acc[ct] = __builtin_amdgcn_mfma_f32_16x16x32_bf16(pa, vf, acc[ct], 0, 0, 0);
            }
        }
    }

    // ---- epilogue: out = gamma*O/l + x ----
    const float gm = gamma_p[0];
    const float li = 1.0f / l_run;
    float lb[4];
    #pragma unroll
    for (int q = 0; q < 4; ++q) lb[q] = __shfl(li, g*4 + q);
    #pragma unroll
    for (int ct = 0; ct < 8; ++ct) {
        const size_t base = ((size_t)b*C_IN + c0 + ct*16 + c16)*N_SP + i0g + 16*w + g*4;
        const float4 xv = *reinterpret_cast<const float4*>(x + base);
        float4 ov;
        ov.x = fmaf(gm, acc[ct][0]*lb[0], xv.x);
        ov.y = fmaf(gm, acc[ct][1]*lb[1], xv.y);
        ov.z = fmaf(gm, acc[ct][2]*lb[2], xv.z);
        ov.w = fmaf(gm, acc[ct][3]*lb[3], xv.w);
        *reinterpret_cast<float4*>(out + base) = ov;
    }
}

extern "C" void kernel_launch(void* const* d_in, const int* in_sizes, int n_in,
                              void* d_out, int out_size, void* d_ws, size_t ws_size,
                              hipStream_t stream)
{
    (void)in_sizes; (void)n_in; (void)out_size; (void)ws_size;
    const float* x  = (const float*)d_in[0];
    const float* Wq = (const float*)d_in[1];
    const float* Wk = (const float*)d_in[2];
    const float* Wv = (const float*)d_in[3];
    const float* gm = (const float*)d_in[4];
    float* out = (float*)d_out;

    // ws: Qb fp32 4MB | Kb fp32 4MB | Qt bf16 2MB | Kt bf16 2MB | V bf16 16MB
    float* Qb = (float*)d_ws;
    float* Kb = Qb + (size_t)4*CQ*N_SP;
    ushort_t* Qt  = (ushort_t*)(Kb + (size_t)4*CQ*N_SP);
    ushort_t* Kt  = Qt + (size_t)4*N_SP*CQ;
    ushort_t* Vbf = Kt + (size_t)4*N_SP*CQ;

    dim3 g1(32, 10, 4);
    proj_qkv<<<g1, 256, 0, stream>>>(x, Wq, Wk, Wv, Qb, Kb, Vbf);
    dim3 g2(64, 2, 4);
    transpose_qk<<<g2, 256, 0, stream>>>(Qb, Kb, Qt, Kt);
    dim3 g3(64, 4, 4);
    attn_mfma<<<g3, 256, 0, stream>>>(x, Qt, Kt, Vbf, gm, out);
}